// Round 13
// baseline (294.383 us; speedup 1.0000x reference)
//
#include <hip/hip_runtime.h>

#define SCAN_CHUNK 2048

typedef short s16x8 __attribute__((ext_vector_type(8)));
typedef float f32x4 __attribute__((ext_vector_type(4)));

__device__ inline ushort f2b(float f) {
  uint u = __float_as_uint(f);
  return (ushort)((u + 0x7fffu + ((u >> 16) & 1u)) >> 16);
}
__device__ inline float b2f(uint h) { return __uint_as_float(h << 16); }

// ---------------- K1: convert (+detect) + atomic hist || weight prep || x->bf16 ----------------
__global__ __launch_bounds__(256) void convert_prep(const void* __restrict__ ei,
                                                    int* __restrict__ src,
                                                    int* __restrict__ dst,
                                                    int* __restrict__ degi, int E,
                                                    const float* __restrict__ W1,
                                                    const float* __restrict__ W2,
                                                    const float* __restrict__ W3,
                                                    const float* __restrict__ F1,
                                                    const float* __restrict__ F2,
                                                    const float* __restrict__ F3,
                                                    const float* __restrict__ x,
                                                    ushort* __restrict__ W1t, ushort* __restrict__ W2t,
                                                    ushort* __restrict__ W3t, ushort* __restrict__ F1t,
                                                    ushort* __restrict__ F2t, ushort* __restrict__ F3t,
                                                    ushort* __restrict__ xb, int N) {
  const int gE = (E + 255) / 256;
  int b = blockIdx.x;
  if (b < gE) {
    __shared__ int sflag;
    if (threadIdx.x == 0) {
      const int* p32 = (const int*)ei;
      int is64 = 1;
#pragma unroll 4
      for (int i = 1; i < 256; i += 2)
        if (p32[i] != 0) { is64 = 0; break; }
      sflag = is64;
    }
    __syncthreads();
    int e = b * 256 + threadIdx.x;
    if (e >= E) return;
    int s, d;
    if (sflag) {
      const long long* p = (const long long*)ei;
      s = (int)p[e];
      d = (int)p[E + e];
    } else {
      const int* p = (const int*)ei;
      s = p[e];
      d = p[E + e];
    }
    src[e] = s;
    dst[e] = d;
    atomicAdd(&degi[d], 1);
  } else if (b < gE + 384) {
    int wi = (b - gE) >> 6;
    int i = ((b - gE) & 63) * 256 + threadIdx.x;
    const float* W;
    ushort* Wt;
    int K, Kp, ncol;
    switch (wi) {
      case 0: W = W1; Wt = W1t; K = 50; Kp = 64; ncol = 128; break;
      case 1: W = W2; Wt = W2t; K = 128; Kp = 128; ncol = 128; break;
      case 2: W = W3; Wt = W3t; K = 128; Kp = 128; ncol = 128; break;
      case 3: W = F1; Wt = F1t; K = 128; Kp = 128; ncol = 128; break;
      case 4: W = F2; Wt = F2t; K = 128; Kp = 128; ncol = 128; break;
      default: W = F3; Wt = F3t; K = 128; Kp = 128; ncol = 121; break;
    }
    if (i >= 128 * Kp) return;
    int c = i / Kp, k = i - c * Kp;
    float w = (k < K && c < ncol) ? W[(size_t)k * ncol + c] : 0.f;
    Wt[(size_t)c * Kp + k] = f2b(w);
  } else {
    long i = (long)(b - gE - 384) * 256 + threadIdx.x;
    if (i >= (long)N * 64) return;
    int n = (int)(i >> 6), k = (int)(i & 63);
    xb[i] = (k < 50) ? f2b(x[(size_t)n * 50 + k]) : (ushort)0;
  }
}

// ---------------- K2: chunk reduce (partial sums for scan) ----------------
__global__ __launch_bounds__(256) void chunk_reduce_kernel(const int* __restrict__ degi,
                                                           int* __restrict__ partials, int N) {
  __shared__ int s[256];
  int base = blockIdx.x * SCAN_CHUNK;
  int sum = 0;
  for (int j = 0; j < 8; ++j) {
    int i = base + threadIdx.x * 8 + j;
    if (i < N) sum += degi[i];
  }
  s[threadIdx.x] = sum;
  __syncthreads();
  for (int ofs = 128; ofs > 0; ofs >>= 1) {
    if ((int)threadIdx.x < ofs) s[threadIdx.x] += s[threadIdx.x + ofs];
    __syncthreads();
  }
  if (threadIdx.x == 0) partials[blockIdx.x] = s[0];
}

// ---------------- K3: chunk scan: rowptr + dinv + zero degi (cnt prep) ----------------
__global__ __launch_bounds__(256) void chunk_scan_kernel(int* __restrict__ degi,
                                                         const int* __restrict__ partials,
                                                         int nchunk,
                                                         int* __restrict__ rowptr,
                                                         float* __restrict__ dinv,
                                                         int N, int E) {
  __shared__ int s[256];
  __shared__ int sbase;
  int t = threadIdx.x;
  if (t == 0) {
    int acc = 0;
    for (int c = 0; c < (int)blockIdx.x; ++c) acc += partials[c];
    sbase = acc;
    if (blockIdx.x == 0) rowptr[N] = E;
  }
  int base = blockIdx.x * SCAN_CHUNK;
  int v[8];
  int tsum = 0;
  for (int j = 0; j < 8; ++j) {
    int i = base + t * 8 + j;
    v[j] = (i < N) ? degi[i] : 0;
    tsum += v[j];
  }
  s[t] = tsum;
  __syncthreads();
  for (int ofs = 1; ofs < 256; ofs <<= 1) {
    int add = (t >= ofs) ? s[t - ofs] : 0;
    __syncthreads();
    s[t] += add;
    __syncthreads();
  }
  int run = s[t] - tsum + sbase;
  for (int j = 0; j < 8; ++j) {
    int i = base + t * 8 + j;
    if (i < N) {
      rowptr[i] = run;
      dinv[i] = rsqrtf((float)v[j] + 1.0f);
      degi[i] = 0;  // becomes cnt for scatter
    }
    run += v[j];
  }
}

// ---------------- K4: XCD-chunked counting-sort scatter ----------------
__global__ __launch_bounds__(256) void scatter_kernel(const int* __restrict__ src,
                                                      const int* __restrict__ dst,
                                                      const int* __restrict__ rowptr,
                                                      const float* __restrict__ dinv,
                                                      int* __restrict__ cnt,
                                                      uint* __restrict__ epack, int E, int N) {
  const int chunk = blockIdx.x & 7;
  const int group = blockIdx.x >> 3;
  const int ngroup = gridDim.x >> 3;
  const int c0 = (int)(((long)chunk * N) >> 3);
  const int c1 = (int)(((long)(chunk + 1) * N) >> 3);
  for (int e = group * 256 + threadIdx.x; e < E; e += ngroup * 256) {
    int d = dst[e];
    if (d < c0 || d >= c1) continue;
    int s = src[e];
    int slot = rowptr[d] + atomicAdd(&cnt[d], 1);
    float nm = dinv[s] * dinv[d];
    epack[slot] = (uint)s | ((uint)f2b(nm) << 16);
  }
}

// ---------------- MFMA matmul: weights in VGPR, grid-stride over 32-row tiles ----------------
template <int KSTEPS, bool BIAS, bool RELU>
__global__ __launch_bounds__(256) void mm_mfma(const ushort* __restrict__ X,
                                               const ushort* __restrict__ Wt,
                                               const float* __restrict__ bias,
                                               ushort* __restrict__ Yb, int N) {
  constexpr int K = KSTEPS * 32;
  const int lane = threadIdx.x & 63;
  const int wq = threadIdx.x >> 6;
  const int am = lane & 15;
  const int ag = lane >> 4;

  s16x8 wf[KSTEPS][2];
#pragma unroll
  for (int ks = 0; ks < KSTEPS; ++ks)
#pragma unroll
    for (int f = 0; f < 2; ++f)
      wf[ks][f] = *(const s16x8*)(Wt + (size_t)(wq * 32 + f * 16 + am) * K + ag * 8 + ks * 32);
  float bv[2] = {0.f, 0.f};
  if (BIAS) {
    bv[0] = bias[wq * 32 + am];
    bv[1] = bias[wq * 32 + 16 + am];
  }

  const int ntile = (N + 31) >> 5;
  for (int t = blockIdx.x; t < ntile; t += gridDim.x) {
    const long r0 = (long)t * 32;
    const bool v1 = (r0 + 16) < N;
    const ushort* x0 = X + (size_t)(r0 + am) * K + ag * 8;
    f32x4 acc[2][2] = {};
#pragma unroll
    for (int ks = 0; ks < KSTEPS; ++ks) {
      s16x8 a0 = *(const s16x8*)(x0 + ks * 32);
      s16x8 a1 = {};
      if (v1) a1 = *(const s16x8*)(x0 + (size_t)16 * K + ks * 32);
#pragma unroll
      for (int f = 0; f < 2; ++f) {
        acc[0][f] = __builtin_amdgcn_mfma_f32_16x16x32_bf16(a0, wf[ks][f], acc[0][f], 0, 0, 0);
        if (v1)
          acc[1][f] = __builtin_amdgcn_mfma_f32_16x16x32_bf16(a1, wf[ks][f], acc[1][f], 0, 0, 0);
      }
    }
#pragma unroll
    for (int m = 0; m < 2; ++m) {
      if (m == 1 && !v1) break;
#pragma unroll
      for (int f = 0; f < 2; ++f) {
        int col = wq * 32 + f * 16 + am;
        float bvv = BIAS ? bv[f] : 0.f;
#pragma unroll
        for (int r = 0; r < 4; ++r) {
          long row = r0 + m * 16 + ag * 4 + r;
          float v = acc[m][f][r] + bvv;
          if (RELU) v = fmaxf(v, 0.f);
          Yb[row * 128 + col] = f2b(v);
        }
      }
    }
  }
}

// ---------------- fc_fused: all 3 FC weight sets in VGPR, grid-stride ----------------
__global__ __launch_bounds__(256) void fc_fused(const ushort* __restrict__ X,
                                                const ushort* __restrict__ F1t,
                                                const ushort* __restrict__ F2t,
                                                const ushort* __restrict__ F3t,
                                                const float* __restrict__ b1,
                                                const float* __restrict__ b2,
                                                const float* __restrict__ b3,
                                                float* __restrict__ out, int N) {
  __shared__ ushort lds[32 * 128];
  const int lane = threadIdx.x & 63;
  const int wq = threadIdx.x >> 6;
  const int am = lane & 15;
  const int ag = lane >> 4;
  char* my = (char*)lds;

  s16x8 wf1[4][2], wf2[4][2], wf3[4][2];
#pragma unroll
  for (int ks = 0; ks < 4; ++ks)
#pragma unroll
    for (int f = 0; f < 2; ++f) {
      size_t o = (size_t)(wq * 32 + f * 16 + am) * 128 + ag * 8 + ks * 32;
      wf1[ks][f] = *(const s16x8*)(F1t + o);
      wf2[ks][f] = *(const s16x8*)(F2t + o);
      wf3[ks][f] = *(const s16x8*)(F3t + o);
    }
  float b1v[2] = {b1[wq * 32 + am], b1[wq * 32 + 16 + am]};
  float b2v[2] = {b2[wq * 32 + am], b2[wq * 32 + 16 + am]};
  int c0 = wq * 32 + am, c1 = wq * 32 + 16 + am;
  float b3v[2] = {(c0 < 121) ? b3[c0] : 0.f, (c1 < 121) ? b3[c1] : 0.f};

  auto stage = [&](f32x4 acc[2][2], const float* bv) {
#pragma unroll
    for (int m = 0; m < 2; ++m)
#pragma unroll
      for (int f = 0; f < 2; ++f) {
        int col = wq * 32 + f * 16 + am;
#pragma unroll
        for (int r = 0; r < 4; ++r) {
          int row = m * 16 + ag * 4 + r;
          uint byte = (uint)(row * 256 + col * 2) ^ ((uint)(row & 7) << 4);
          *(ushort*)(my + byte) = f2b(fmaxf(acc[m][f][r] + bv[f], 0.f));
        }
      }
  };
  auto loadA = [&](int m, int ks) -> s16x8 {
    int row = m * 16 + am;
    uint byte = (uint)(row * 256 + ks * 64 + ag * 16) ^ ((uint)(row & 7) << 4);
    return *(const s16x8*)(my + byte);
  };

  const int ntile = (N + 31) >> 5;
  for (int t = blockIdx.x; t < ntile; t += gridDim.x) {
    const long r0 = (long)t * 32;
    const bool v1 = (r0 + 16) < N;
    const ushort* x0 = X + (size_t)(r0 + am) * 128 + ag * 8;

    f32x4 a1c[2][2] = {};
#pragma unroll
    for (int ks = 0; ks < 4; ++ks) {
      s16x8 a0 = *(const s16x8*)(x0 + ks * 32);
      s16x8 a1 = v1 ? *(const s16x8*)(x0 + (size_t)16 * 128 + ks * 32) : s16x8{};
#pragma unroll
      for (int f = 0; f < 2; ++f) {
        a1c[0][f] = __builtin_amdgcn_mfma_f32_16x16x32_bf16(a0, wf1[ks][f], a1c[0][f], 0, 0, 0);
        a1c[1][f] = __builtin_amdgcn_mfma_f32_16x16x32_bf16(a1, wf1[ks][f], a1c[1][f], 0, 0, 0);
      }
    }
    stage(a1c, b1v);
    __syncthreads();
    f32x4 a2c[2][2] = {};
#pragma unroll
    for (int ks = 0; ks < 4; ++ks) {
      s16x8 a0 = loadA(0, ks);
      s16x8 a1 = loadA(1, ks);
#pragma unroll
      for (int f = 0; f < 2; ++f) {
        a2c[0][f] = __builtin_amdgcn_mfma_f32_16x16x32_bf16(a0, wf2[ks][f], a2c[0][f], 0, 0, 0);
        a2c[1][f] = __builtin_amdgcn_mfma_f32_16x16x32_bf16(a1, wf2[ks][f], a2c[1][f], 0, 0, 0);
      }
    }
    __syncthreads();
    stage(a2c, b2v);
    __syncthreads();
    f32x4 a3c[2][2] = {};
#pragma unroll
    for (int ks = 0; ks < 4; ++ks) {
      s16x8 a0 = loadA(0, ks);
      s16x8 a1 = loadA(1, ks);
#pragma unroll
      for (int f = 0; f < 2; ++f) {
        a3c[0][f] = __builtin_amdgcn_mfma_f32_16x16x32_bf16(a0, wf3[ks][f], a3c[0][f], 0, 0, 0);
        a3c[1][f] = __builtin_amdgcn_mfma_f32_16x16x32_bf16(a1, wf3[ks][f], a3c[1][f], 0, 0, 0);
      }
    }
#pragma unroll
    for (int m = 0; m < 2; ++m) {
      if (m == 1 && !v1) break;
#pragma unroll
      for (int f = 0; f < 2; ++f) {
        int col = wq * 32 + f * 16 + am;
        if (col >= 121) continue;
#pragma unroll
        for (int r = 0; r < 4; ++r) {
          long row = r0 + m * 16 + ag * 4 + r;
          out[row * 121 + col] = a3c[m][f][r] + b3v[f];
        }
      }
    }
    __syncthreads();
  }
}

// ---------------- CSR aggregation, TWO waves per node (split edge list, LDS combine) ----------------
// Block = 4 waves = 2 nodes. Wave pair (sub=0: first half, sub=1: second half) each runs the
// 8-deep pipelined gather on its half; sub1 deposits partials in LDS; sub0 combines + epilogue.
template <int RW, bool ACT>
__global__ __launch_bounds__(256) void agg_kernel(const ushort* __restrict__ Hm,
                                                  const int* __restrict__ rowptr,
                                                  const uint* __restrict__ epack,
                                                  const float* __restrict__ dinv,
                                                  const float* __restrict__ b,
                                                  ushort* __restrict__ Y, int N) {
  __shared__ float2 part[2][64];
  int wave = threadIdx.x >> 6;
  int lane = threadIdx.x & 63;
  int pair = wave >> 1;
  int sub = wave & 1;
  long n = (long)blockIdx.x * 2 + pair;
  bool valid = n < N;
  int beg = 0, end = 0;
  if (valid) {
    beg = rowptr[n];
    end = rowptr[n + 1];
  }
  int mid = beg + ((end - beg + 1) >> 1);
  int i = sub ? mid : beg;
  int hi = sub ? end : mid;

  float ax = 0.f, ay = 0.f;
  if constexpr (RW == 128) {
    int f = lane * 2;
    while (i + 8 <= hi) {
      uint rec[8];
#pragma unroll
      for (int j = 0; j < 8; ++j) rec[j] = epack[i + j];
      uint v[8];
#pragma unroll
      for (int j = 0; j < 8; ++j)
        v[j] = *(const uint*)&Hm[(size_t)(rec[j] & 0xffffu) * 128 + f];
#pragma unroll
      for (int j = 0; j < 8; ++j) {
        float nm = __uint_as_float(rec[j] & 0xffff0000u);
        ax += b2f(v[j] & 0xffffu) * nm;
        ay += b2f(v[j] >> 16) * nm;
      }
      i += 8;
    }
    if (i + 4 <= hi) {
      uint rec[4];
#pragma unroll
      for (int j = 0; j < 4; ++j) rec[j] = epack[i + j];
      uint v[4];
#pragma unroll
      for (int j = 0; j < 4; ++j)
        v[j] = *(const uint*)&Hm[(size_t)(rec[j] & 0xffffu) * 128 + f];
#pragma unroll
      for (int j = 0; j < 4; ++j) {
        float nm = __uint_as_float(rec[j] & 0xffff0000u);
        ax += b2f(v[j] & 0xffffu) * nm;
        ay += b2f(v[j] >> 16) * nm;
      }
      i += 4;
    }
    for (; i < hi; ++i) {
      uint rec = epack[i];
      float nm = __uint_as_float(rec & 0xffff0000u);
      uint v = *(const uint*)&Hm[(size_t)(rec & 0xffffu) * 128 + f];
      ax += b2f(v & 0xffffu) * nm;
      ay += b2f(v >> 16) * nm;
    }
  } else {
    int f = lane;
    while (i + 8 <= hi) {
      uint rec[8];
#pragma unroll
      for (int j = 0; j < 8; ++j) rec[j] = epack[i + j];
      ushort v[8];
#pragma unroll
      for (int j = 0; j < 8; ++j)
        v[j] = Hm[(size_t)(rec[j] & 0xffffu) * 64 + f];
#pragma unroll
      for (int j = 0; j < 8; ++j)
        ax += b2f(v[j]) * __uint_as_float(rec[j] & 0xffff0000u);
      i += 8;
    }
    if (i + 4 <= hi) {
      uint rec[4];
#pragma unroll
      for (int j = 0; j < 4; ++j) rec[j] = epack[i + j];
      ushort v[4];
#pragma unroll
      for (int j = 0; j < 4; ++j)
        v[j] = Hm[(size_t)(rec[j] & 0xffffu) * 64 + f];
#pragma unroll
      for (int j = 0; j < 4; ++j)
        ax += b2f(v[j]) * __uint_as_float(rec[j] & 0xffff0000u);
      i += 4;
    }
    for (; i < hi; ++i) {
      uint rec = epack[i];
      ax += b2f(Hm[(size_t)(rec & 0xffffu) * 64 + f]) * __uint_as_float(rec & 0xffff0000u);
    }
  }

  if (sub == 1) part[pair][lane] = make_float2(ax, ay);
  __syncthreads();
  if (sub == 0 && valid) {
    float2 o = part[pair][lane];
    ax += o.x;
    ay += o.y;
    float dn = dinv[n];
    float d2 = dn * dn;
    if constexpr (RW == 128) {
      int f = lane * 2;
      uint sv = *(const uint*)&Hm[(size_t)n * 128 + f];
      ax += b2f(sv & 0xffffu) * d2;
      ay += b2f(sv >> 16) * d2;
      if (ACT) {
        ax = fmaxf(ax + b[f], 0.f);
        ay = fmaxf(ay + b[f + 1], 0.f);
      }
      uint outv = (uint)f2b(ax) | ((uint)f2b(ay) << 16);
      *(uint*)&Y[(size_t)n * 128 + f] = outv;
    } else {
      int f = lane;
      ax += b2f(Hm[(size_t)n * 64 + f]) * d2;
      if (ACT) ax = fmaxf(ax + b[f], 0.f);
      Y[(size_t)n * 64 + f] = f2b(ax);
    }
  }
}

// ---------------- launch ----------------
extern "C" void kernel_launch(void* const* d_in, const int* in_sizes, int n_in,
                              void* d_out, int out_size, void* d_ws, size_t ws_size,
                              hipStream_t stream) {
  const float* x    = (const float*)d_in[0];
  const void*  ei   = d_in[1];
  const float* W1   = (const float*)d_in[3];
  const float* b1   = (const float*)d_in[4];
  const float* W2   = (const float*)d_in[5];
  const float* b2   = (const float*)d_in[6];
  const float* W3   = (const float*)d_in[7];
  const float* b3   = (const float*)d_in[8];
  const float* fcW1 = (const float*)d_in[9];
  const float* fcb1 = (const float*)d_in[10];
  const float* fcW2 = (const float*)d_in[11];
  const float* fcb2 = (const float*)d_in[12];
  const float* fcW3 = (const float*)d_in[13];
  const float* fcb3 = (const float*)d_in[14];

  const int FIN = 50;
  const int N = in_sizes[0] / FIN;
  const int E = in_sizes[1] / 2;
  const int NCHUNK = (N + SCAN_CHUNK - 1) / SCAN_CHUNK;

  size_t off = 0;
  auto carve = [&](size_t bytes) {
    void* p = (char*)d_ws + off;
    off += (bytes + 255) & ~(size_t)255;
    return p;
  };
  int*    src32    = (int*)carve((size_t)E * 4);
  int*    dst32    = (int*)carve((size_t)E * 4);
  uint*   epack    = (uint*)carve((size_t)E * 4);
  int*    degi     = (int*)carve((size_t)(N + 4) * 4);
  int*    rowptr   = (int*)carve((size_t)(N + 1) * 4);
  float*  dinv     = (float*)carve((size_t)N * 4);
  int*    partials = (int*)carve((size_t)NCHUNK * 4);
  ushort* W1t      = (ushort*)carve((size_t)128 * 64 * 2);
  ushort* W2t      = (ushort*)carve((size_t)128 * 128 * 2);
  ushort* W3t      = (ushort*)carve((size_t)128 * 128 * 2);
  ushort* F1t      = (ushort*)carve((size_t)128 * 128 * 2);
  ushort* F2t      = (ushort*)carve((size_t)128 * 128 * 2);
  ushort* F3t      = (ushort*)carve((size_t)128 * 128 * 2);
  ushort* xb       = (ushort*)carve((size_t)N * 64 * 2);
  ushort* aggX     = (ushort*)carve((size_t)N * 64 * 2);
  ushort* bufA     = (ushort*)carve((size_t)N * 128 * 2);
  ushort* bufB     = (ushort*)carve((size_t)N * 128 * 2);

  const int gE = (E + 255) / 256;
  const int gXB = (int)(((long)N * 64 + 255) / 256);
  const int gMM = 1024;
  const int gAGG = (N + 1) / 2;  // 2 nodes per block (2 waves per node)

  // --- graph preprocessing ---
  hipMemsetAsync(degi, 0, (size_t)N * 4, stream);
  convert_prep<<<gE + 384 + gXB, 256, 0, stream>>>(ei, src32, dst32, degi, E,
                                                   W1, W2, W3, fcW1, fcW2, fcW3, x,
                                                   W1t, W2t, W3t, F1t, F2t, F3t, xb, N);
  chunk_reduce_kernel<<<NCHUNK, 256, 0, stream>>>(degi, partials, N);
  chunk_scan_kernel<<<NCHUNK, 256, 0, stream>>>(degi, partials, NCHUNK, rowptr, dinv, N, E);
  scatter_kernel<<<1024, 256, 0, stream>>>(src32, dst32, rowptr, dinv, degi, epack, E, N);

  // --- conv layer 1 (aggregate 64-wide input, then mm with fused bias+relu) ---
  agg_kernel<64, false><<<gAGG, 256, 0, stream>>>(xb, rowptr, epack, dinv, nullptr, aggX, N);
  mm_mfma<2, true, true><<<gMM, 256, 0, stream>>>(aggX, W1t, b1, bufA, N);
  // --- conv layer 2 ---
  mm_mfma<4, false, false><<<gMM, 256, 0, stream>>>(bufA, W2t, nullptr, bufB, N);
  agg_kernel<128, true><<<gAGG, 256, 0, stream>>>(bufB, rowptr, epack, dinv, b2, bufA, N);
  // --- conv layer 3 ---
  mm_mfma<4, false, false><<<gMM, 256, 0, stream>>>(bufA, W3t, nullptr, bufB, N);
  agg_kernel<128, true><<<gAGG, 256, 0, stream>>>(bufB, rowptr, epack, dinv, b3, bufA, N);
  // --- fused FC head ---
  fc_fused<<<gMM, 256, 0, stream>>>(bufA, F1t, F2t, F3t, fcb1, fcb2, fcb3,
                                    (float*)d_out, N);
}

// Round 14
// 256.259 us; speedup vs baseline: 1.1488x; 1.1488x over previous
//
#include <hip/hip_runtime.h>

#define SCAN_CHUNK 2048

typedef short s16x8 __attribute__((ext_vector_type(8)));
typedef float f32x4 __attribute__((ext_vector_type(4)));

__device__ inline ushort f2b(float f) {
  uint u = __float_as_uint(f);
  return (ushort)((u + 0x7fffu + ((u >> 16) & 1u)) >> 16);
}
__device__ inline float b2f(uint h) { return __uint_as_float(h << 16); }

// ---------------- K1: convert (+detect) + atomic hist || weight prep || x->bf16 ----------------
__global__ __launch_bounds__(256) void convert_prep(const void* __restrict__ ei,
                                                    int* __restrict__ src,
                                                    int* __restrict__ dst,
                                                    int* __restrict__ degi, int E,
                                                    const float* __restrict__ W1,
                                                    const float* __restrict__ W2,
                                                    const float* __restrict__ W3,
                                                    const float* __restrict__ F1,
                                                    const float* __restrict__ F2,
                                                    const float* __restrict__ F3,
                                                    const float* __restrict__ x,
                                                    ushort* __restrict__ W1t, ushort* __restrict__ W2t,
                                                    ushort* __restrict__ W3t, ushort* __restrict__ F1t,
                                                    ushort* __restrict__ F2t, ushort* __restrict__ F3t,
                                                    ushort* __restrict__ xb, int N) {
  const int gE = (E + 255) / 256;
  int b = blockIdx.x;
  if (b < gE) {
    __shared__ int sflag;
    if (threadIdx.x == 0) {
      const int* p32 = (const int*)ei;
      int is64 = 1;
#pragma unroll 4
      for (int i = 1; i < 256; i += 2)
        if (p32[i] != 0) { is64 = 0; break; }
      sflag = is64;
    }
    __syncthreads();
    int e = b * 256 + threadIdx.x;
    if (e >= E) return;
    int s, d;
    if (sflag) {
      const long long* p = (const long long*)ei;
      s = (int)p[e];
      d = (int)p[E + e];
    } else {
      const int* p = (const int*)ei;
      s = p[e];
      d = p[E + e];
    }
    src[e] = s;
    dst[e] = d;
    atomicAdd(&degi[d], 1);
  } else if (b < gE + 384) {
    int wi = (b - gE) >> 6;
    int i = ((b - gE) & 63) * 256 + threadIdx.x;
    const float* W;
    ushort* Wt;
    int K, Kp, ncol;
    switch (wi) {
      case 0: W = W1; Wt = W1t; K = 50; Kp = 64; ncol = 128; break;
      case 1: W = W2; Wt = W2t; K = 128; Kp = 128; ncol = 128; break;
      case 2: W = W3; Wt = W3t; K = 128; Kp = 128; ncol = 128; break;
      case 3: W = F1; Wt = F1t; K = 128; Kp = 128; ncol = 128; break;
      case 4: W = F2; Wt = F2t; K = 128; Kp = 128; ncol = 128; break;
      default: W = F3; Wt = F3t; K = 128; Kp = 128; ncol = 121; break;
    }
    if (i >= 128 * Kp) return;
    int c = i / Kp, k = i - c * Kp;
    float w = (k < K && c < ncol) ? W[(size_t)k * ncol + c] : 0.f;
    Wt[(size_t)c * Kp + k] = f2b(w);
  } else {
    long i = (long)(b - gE - 384) * 256 + threadIdx.x;
    if (i >= (long)N * 64) return;
    int n = (int)(i >> 6), k = (int)(i & 63);
    xb[i] = (k < 50) ? f2b(x[(size_t)n * 50 + k]) : (ushort)0;
  }
}

// ---------------- K2: chunk reduce (partial sums for scan) ----------------
__global__ __launch_bounds__(256) void chunk_reduce_kernel(const int* __restrict__ degi,
                                                           int* __restrict__ partials, int N) {
  __shared__ int s[256];
  int base = blockIdx.x * SCAN_CHUNK;
  int sum = 0;
  for (int j = 0; j < 8; ++j) {
    int i = base + threadIdx.x * 8 + j;
    if (i < N) sum += degi[i];
  }
  s[threadIdx.x] = sum;
  __syncthreads();
  for (int ofs = 128; ofs > 0; ofs >>= 1) {
    if ((int)threadIdx.x < ofs) s[threadIdx.x] += s[threadIdx.x + ofs];
    __syncthreads();
  }
  if (threadIdx.x == 0) partials[blockIdx.x] = s[0];
}

// ---------------- K3: chunk scan: rowptr + dinv + zero degi (cnt prep) ----------------
__global__ __launch_bounds__(256) void chunk_scan_kernel(int* __restrict__ degi,
                                                         const int* __restrict__ partials,
                                                         int nchunk,
                                                         int* __restrict__ rowptr,
                                                         float* __restrict__ dinv,
                                                         int N, int E) {
  __shared__ int s[256];
  __shared__ int sbase;
  int t = threadIdx.x;
  if (t == 0) {
    int acc = 0;
    for (int c = 0; c < (int)blockIdx.x; ++c) acc += partials[c];
    sbase = acc;
    if (blockIdx.x == 0) rowptr[N] = E;
  }
  int base = blockIdx.x * SCAN_CHUNK;
  int v[8];
  int tsum = 0;
  for (int j = 0; j < 8; ++j) {
    int i = base + t * 8 + j;
    v[j] = (i < N) ? degi[i] : 0;
    tsum += v[j];
  }
  s[t] = tsum;
  __syncthreads();
  for (int ofs = 1; ofs < 256; ofs <<= 1) {
    int add = (t >= ofs) ? s[t - ofs] : 0;
    __syncthreads();
    s[t] += add;
    __syncthreads();
  }
  int run = s[t] - tsum + sbase;
  for (int j = 0; j < 8; ++j) {
    int i = base + t * 8 + j;
    if (i < N) {
      rowptr[i] = run;
      dinv[i] = rsqrtf((float)v[j] + 1.0f);
      degi[i] = 0;  // becomes cnt for scatter
    }
    run += v[j];
  }
}

// ---------------- K4: XCD-chunked counting-sort scatter ----------------
__global__ __launch_bounds__(256) void scatter_kernel(const int* __restrict__ src,
                                                      const int* __restrict__ dst,
                                                      const int* __restrict__ rowptr,
                                                      const float* __restrict__ dinv,
                                                      int* __restrict__ cnt,
                                                      uint* __restrict__ epack, int E, int N) {
  const int chunk = blockIdx.x & 7;
  const int group = blockIdx.x >> 3;
  const int ngroup = gridDim.x >> 3;
  const int c0 = (int)(((long)chunk * N) >> 3);
  const int c1 = (int)(((long)(chunk + 1) * N) >> 3);
  for (int e = group * 256 + threadIdx.x; e < E; e += ngroup * 256) {
    int d = dst[e];
    if (d < c0 || d >= c1) continue;
    int s = src[e];
    int slot = rowptr[d] + atomicAdd(&cnt[d], 1);
    float nm = dinv[s] * dinv[d];
    epack[slot] = (uint)s | ((uint)f2b(nm) << 16);
  }
}

// ---------------- MFMA matmul: weights in VGPR, grid-stride over 32-row tiles ----------------
template <int KSTEPS, bool BIAS, bool RELU>
__global__ __launch_bounds__(256) void mm_mfma(const ushort* __restrict__ X,
                                               const ushort* __restrict__ Wt,
                                               const float* __restrict__ bias,
                                               ushort* __restrict__ Yb, int N) {
  constexpr int K = KSTEPS * 32;
  const int lane = threadIdx.x & 63;
  const int wq = threadIdx.x >> 6;
  const int am = lane & 15;
  const int ag = lane >> 4;

  s16x8 wf[KSTEPS][2];
#pragma unroll
  for (int ks = 0; ks < KSTEPS; ++ks)
#pragma unroll
    for (int f = 0; f < 2; ++f)
      wf[ks][f] = *(const s16x8*)(Wt + (size_t)(wq * 32 + f * 16 + am) * K + ag * 8 + ks * 32);
  float bv[2] = {0.f, 0.f};
  if (BIAS) {
    bv[0] = bias[wq * 32 + am];
    bv[1] = bias[wq * 32 + 16 + am];
  }

  const int ntile = (N + 31) >> 5;
  for (int t = blockIdx.x; t < ntile; t += gridDim.x) {
    const long r0 = (long)t * 32;
    const bool v1 = (r0 + 16) < N;
    const ushort* x0 = X + (size_t)(r0 + am) * K + ag * 8;
    f32x4 acc[2][2] = {};
#pragma unroll
    for (int ks = 0; ks < KSTEPS; ++ks) {
      s16x8 a0 = *(const s16x8*)(x0 + ks * 32);
      s16x8 a1 = {};
      if (v1) a1 = *(const s16x8*)(x0 + (size_t)16 * K + ks * 32);
#pragma unroll
      for (int f = 0; f < 2; ++f) {
        acc[0][f] = __builtin_amdgcn_mfma_f32_16x16x32_bf16(a0, wf[ks][f], acc[0][f], 0, 0, 0);
        if (v1)
          acc[1][f] = __builtin_amdgcn_mfma_f32_16x16x32_bf16(a1, wf[ks][f], acc[1][f], 0, 0, 0);
      }
    }
#pragma unroll
    for (int m = 0; m < 2; ++m) {
      if (m == 1 && !v1) break;
#pragma unroll
      for (int f = 0; f < 2; ++f) {
        int col = wq * 32 + f * 16 + am;
        float bvv = BIAS ? bv[f] : 0.f;
#pragma unroll
        for (int r = 0; r < 4; ++r) {
          long row = r0 + m * 16 + ag * 4 + r;
          float v = acc[m][f][r] + bvv;
          if (RELU) v = fmaxf(v, 0.f);
          Yb[row * 128 + col] = f2b(v);
        }
      }
    }
  }
}

// ---------------- fc_fused: all 3 FC weight sets in VGPR, grid-stride ----------------
__global__ __launch_bounds__(256) void fc_fused(const ushort* __restrict__ X,
                                                const ushort* __restrict__ F1t,
                                                const ushort* __restrict__ F2t,
                                                const ushort* __restrict__ F3t,
                                                const float* __restrict__ b1,
                                                const float* __restrict__ b2,
                                                const float* __restrict__ b3,
                                                float* __restrict__ out, int N) {
  __shared__ ushort lds[32 * 128];
  const int lane = threadIdx.x & 63;
  const int wq = threadIdx.x >> 6;
  const int am = lane & 15;
  const int ag = lane >> 4;
  char* my = (char*)lds;

  s16x8 wf1[4][2], wf2[4][2], wf3[4][2];
#pragma unroll
  for (int ks = 0; ks < 4; ++ks)
#pragma unroll
    for (int f = 0; f < 2; ++f) {
      size_t o = (size_t)(wq * 32 + f * 16 + am) * 128 + ag * 8 + ks * 32;
      wf1[ks][f] = *(const s16x8*)(F1t + o);
      wf2[ks][f] = *(const s16x8*)(F2t + o);
      wf3[ks][f] = *(const s16x8*)(F3t + o);
    }
  float b1v[2] = {b1[wq * 32 + am], b1[wq * 32 + 16 + am]};
  float b2v[2] = {b2[wq * 32 + am], b2[wq * 32 + 16 + am]};
  int c0 = wq * 32 + am, c1 = wq * 32 + 16 + am;
  float b3v[2] = {(c0 < 121) ? b3[c0] : 0.f, (c1 < 121) ? b3[c1] : 0.f};

  auto stage = [&](f32x4 acc[2][2], const float* bv) {
#pragma unroll
    for (int m = 0; m < 2; ++m)
#pragma unroll
      for (int f = 0; f < 2; ++f) {
        int col = wq * 32 + f * 16 + am;
#pragma unroll
        for (int r = 0; r < 4; ++r) {
          int row = m * 16 + ag * 4 + r;
          uint byte = (uint)(row * 256 + col * 2) ^ ((uint)(row & 7) << 4);
          *(ushort*)(my + byte) = f2b(fmaxf(acc[m][f][r] + bv[f], 0.f));
        }
      }
  };
  auto loadA = [&](int m, int ks) -> s16x8 {
    int row = m * 16 + am;
    uint byte = (uint)(row * 256 + ks * 64 + ag * 16) ^ ((uint)(row & 7) << 4);
    return *(const s16x8*)(my + byte);
  };

  const int ntile = (N + 31) >> 5;
  for (int t = blockIdx.x; t < ntile; t += gridDim.x) {
    const long r0 = (long)t * 32;
    const bool v1 = (r0 + 16) < N;
    const ushort* x0 = X + (size_t)(r0 + am) * 128 + ag * 8;

    f32x4 a1c[2][2] = {};
#pragma unroll
    for (int ks = 0; ks < 4; ++ks) {
      s16x8 a0 = *(const s16x8*)(x0 + ks * 32);
      s16x8 a1 = v1 ? *(const s16x8*)(x0 + (size_t)16 * 128 + ks * 32) : s16x8{};
#pragma unroll
      for (int f = 0; f < 2; ++f) {
        a1c[0][f] = __builtin_amdgcn_mfma_f32_16x16x32_bf16(a0, wf1[ks][f], a1c[0][f], 0, 0, 0);
        a1c[1][f] = __builtin_amdgcn_mfma_f32_16x16x32_bf16(a1, wf1[ks][f], a1c[1][f], 0, 0, 0);
      }
    }
    stage(a1c, b1v);
    __syncthreads();
    f32x4 a2c[2][2] = {};
#pragma unroll
    for (int ks = 0; ks < 4; ++ks) {
      s16x8 a0 = loadA(0, ks);
      s16x8 a1 = loadA(1, ks);
#pragma unroll
      for (int f = 0; f < 2; ++f) {
        a2c[0][f] = __builtin_amdgcn_mfma_f32_16x16x32_bf16(a0, wf2[ks][f], a2c[0][f], 0, 0, 0);
        a2c[1][f] = __builtin_amdgcn_mfma_f32_16x16x32_bf16(a1, wf2[ks][f], a2c[1][f], 0, 0, 0);
      }
    }
    __syncthreads();
    stage(a2c, b2v);
    __syncthreads();
    f32x4 a3c[2][2] = {};
#pragma unroll
    for (int ks = 0; ks < 4; ++ks) {
      s16x8 a0 = loadA(0, ks);
      s16x8 a1 = loadA(1, ks);
#pragma unroll
      for (int f = 0; f < 2; ++f) {
        a3c[0][f] = __builtin_amdgcn_mfma_f32_16x16x32_bf16(a0, wf3[ks][f], a3c[0][f], 0, 0, 0);
        a3c[1][f] = __builtin_amdgcn_mfma_f32_16x16x32_bf16(a1, wf3[ks][f], a3c[1][f], 0, 0, 0);
      }
    }
#pragma unroll
    for (int m = 0; m < 2; ++m) {
      if (m == 1 && !v1) break;
#pragma unroll
      for (int f = 0; f < 2; ++f) {
        int col = wq * 32 + f * 16 + am;
        if (col >= 121) continue;
#pragma unroll
        for (int r = 0; r < 4; ++r) {
          long row = r0 + m * 16 + ag * 4 + r;
          out[row * 121 + col] = a3c[m][f][r] + b3v[f];
        }
      }
    }
    __syncthreads();
  }
}

// ---------------- CSR aggregation, one wave per node, 16-deep pipelined gather ----------------
template <int RW, bool ACT>
__global__ __launch_bounds__(256) void agg_kernel(const ushort* __restrict__ Hm,
                                                  const int* __restrict__ rowptr,
                                                  const uint* __restrict__ epack,
                                                  const float* __restrict__ dinv,
                                                  const float* __restrict__ b,
                                                  ushort* __restrict__ Y, int N) {
  int wave = threadIdx.x >> 6;
  int lane = threadIdx.x & 63;
  int n = blockIdx.x * 4 + wave;
  if (n >= N) return;
  int beg = rowptr[n], end = rowptr[n + 1];
  float dn = dinv[n];
  float d2 = dn * dn;
  int i = beg;

  if constexpr (RW == 128) {
    int f = lane * 2;
    float ax = 0.f, ay = 0.f;
    while (i + 16 <= end) {
      uint rec[16];
#pragma unroll
      for (int j = 0; j < 16; ++j) rec[j] = epack[i + j];
      uint v[16];
#pragma unroll
      for (int j = 0; j < 16; ++j)
        v[j] = *(const uint*)&Hm[(size_t)(rec[j] & 0xffffu) * 128 + f];
#pragma unroll
      for (int j = 0; j < 16; ++j) {
        float nm = __uint_as_float(rec[j] & 0xffff0000u);
        ax += b2f(v[j] & 0xffffu) * nm;
        ay += b2f(v[j] >> 16) * nm;
      }
      i += 16;
    }
    if (i + 8 <= end) {
      uint rec[8];
#pragma unroll
      for (int j = 0; j < 8; ++j) rec[j] = epack[i + j];
      uint v[8];
#pragma unroll
      for (int j = 0; j < 8; ++j)
        v[j] = *(const uint*)&Hm[(size_t)(rec[j] & 0xffffu) * 128 + f];
#pragma unroll
      for (int j = 0; j < 8; ++j) {
        float nm = __uint_as_float(rec[j] & 0xffff0000u);
        ax += b2f(v[j] & 0xffffu) * nm;
        ay += b2f(v[j] >> 16) * nm;
      }
      i += 8;
    }
    if (i + 4 <= end) {
      uint rec[4];
#pragma unroll
      for (int j = 0; j < 4; ++j) rec[j] = epack[i + j];
      uint v[4];
#pragma unroll
      for (int j = 0; j < 4; ++j)
        v[j] = *(const uint*)&Hm[(size_t)(rec[j] & 0xffffu) * 128 + f];
#pragma unroll
      for (int j = 0; j < 4; ++j) {
        float nm = __uint_as_float(rec[j] & 0xffff0000u);
        ax += b2f(v[j] & 0xffffu) * nm;
        ay += b2f(v[j] >> 16) * nm;
      }
      i += 4;
    }
    for (; i < end; ++i) {
      uint rec = epack[i];
      float nm = __uint_as_float(rec & 0xffff0000u);
      uint v = *(const uint*)&Hm[(size_t)(rec & 0xffffu) * 128 + f];
      ax += b2f(v & 0xffffu) * nm;
      ay += b2f(v >> 16) * nm;
    }
    uint sv = *(const uint*)&Hm[(size_t)n * 128 + f];
    ax += b2f(sv & 0xffffu) * d2;
    ay += b2f(sv >> 16) * d2;
    if (ACT) {
      ax = fmaxf(ax + b[f], 0.f);
      ay = fmaxf(ay + b[f + 1], 0.f);
    }
    uint out = (uint)f2b(ax) | ((uint)f2b(ay) << 16);
    *(uint*)&Y[(size_t)n * 128 + f] = out;
  } else {
    int f = lane;
    float ax = 0.f;
    while (i + 16 <= end) {
      uint rec[16];
#pragma unroll
      for (int j = 0; j < 16; ++j) rec[j] = epack[i + j];
      ushort v[16];
#pragma unroll
      for (int j = 0; j < 16; ++j)
        v[j] = Hm[(size_t)(rec[j] & 0xffffu) * 64 + f];
#pragma unroll
      for (int j = 0; j < 16; ++j)
        ax += b2f(v[j]) * __uint_as_float(rec[j] & 0xffff0000u);
      i += 16;
    }
    if (i + 8 <= end) {
      uint rec[8];
#pragma unroll
      for (int j = 0; j < 8; ++j) rec[j] = epack[i + j];
      ushort v[8];
#pragma unroll
      for (int j = 0; j < 8; ++j)
        v[j] = Hm[(size_t)(rec[j] & 0xffffu) * 64 + f];
#pragma unroll
      for (int j = 0; j < 8; ++j)
        ax += b2f(v[j]) * __uint_as_float(rec[j] & 0xffff0000u);
      i += 8;
    }
    if (i + 4 <= end) {
      uint rec[4];
#pragma unroll
      for (int j = 0; j < 4; ++j) rec[j] = epack[i + j];
      ushort v[4];
#pragma unroll
      for (int j = 0; j < 4; ++j)
        v[j] = Hm[(size_t)(rec[j] & 0xffffu) * 64 + f];
#pragma unroll
      for (int j = 0; j < 4; ++j)
        ax += b2f(v[j]) * __uint_as_float(rec[j] & 0xffff0000u);
      i += 4;
    }
    for (; i < end; ++i) {
      uint rec = epack[i];
      ax += b2f(Hm[(size_t)(rec & 0xffffu) * 64 + f]) * __uint_as_float(rec & 0xffff0000u);
    }
    ax += b2f(Hm[(size_t)n * 64 + f]) * d2;
    if (ACT) ax = fmaxf(ax + b[f], 0.f);
    Y[(size_t)n * 64 + f] = f2b(ax);
  }
}

// ---------------- launch ----------------
extern "C" void kernel_launch(void* const* d_in, const int* in_sizes, int n_in,
                              void* d_out, int out_size, void* d_ws, size_t ws_size,
                              hipStream_t stream) {
  const float* x    = (const float*)d_in[0];
  const void*  ei   = d_in[1];
  const float* W1   = (const float*)d_in[3];
  const float* b1   = (const float*)d_in[4];
  const float* W2   = (const float*)d_in[5];
  const float* b2   = (const float*)d_in[6];
  const float* W3   = (const float*)d_in[7];
  const float* b3   = (const float*)d_in[8];
  const float* fcW1 = (const float*)d_in[9];
  const float* fcb1 = (const float*)d_in[10];
  const float* fcW2 = (const float*)d_in[11];
  const float* fcb2 = (const float*)d_in[12];
  const float* fcW3 = (const float*)d_in[13];
  const float* fcb3 = (const float*)d_in[14];

  const int FIN = 50;
  const int N = in_sizes[0] / FIN;
  const int E = in_sizes[1] / 2;
  const int NCHUNK = (N + SCAN_CHUNK - 1) / SCAN_CHUNK;

  size_t off = 0;
  auto carve = [&](size_t bytes) {
    void* p = (char*)d_ws + off;
    off += (bytes + 255) & ~(size_t)255;
    return p;
  };
  int*    src32    = (int*)carve((size_t)E * 4);
  int*    dst32    = (int*)carve((size_t)E * 4);
  uint*   epack    = (uint*)carve((size_t)E * 4);
  int*    degi     = (int*)carve((size_t)(N + 4) * 4);
  int*    rowptr   = (int*)carve((size_t)(N + 1) * 4);
  float*  dinv     = (float*)carve((size_t)N * 4);
  int*    partials = (int*)carve((size_t)NCHUNK * 4);
  ushort* W1t      = (ushort*)carve((size_t)128 * 64 * 2);
  ushort* W2t      = (ushort*)carve((size_t)128 * 128 * 2);
  ushort* W3t      = (ushort*)carve((size_t)128 * 128 * 2);
  ushort* F1t      = (ushort*)carve((size_t)128 * 128 * 2);
  ushort* F2t      = (ushort*)carve((size_t)128 * 128 * 2);
  ushort* F3t      = (ushort*)carve((size_t)128 * 128 * 2);
  ushort* xb       = (ushort*)carve((size_t)N * 64 * 2);
  ushort* aggX     = (ushort*)carve((size_t)N * 64 * 2);
  ushort* bufA     = (ushort*)carve((size_t)N * 128 * 2);
  ushort* bufB     = (ushort*)carve((size_t)N * 128 * 2);

  const int gE = (E + 255) / 256;
  const int gXB = (int)(((long)N * 64 + 255) / 256);
  const int gMM = 1024;
  const int gAGG = (N + 3) / 4;

  // --- graph preprocessing ---
  hipMemsetAsync(degi, 0, (size_t)N * 4, stream);
  convert_prep<<<gE + 384 + gXB, 256, 0, stream>>>(ei, src32, dst32, degi, E,
                                                   W1, W2, W3, fcW1, fcW2, fcW3, x,
                                                   W1t, W2t, W3t, F1t, F2t, F3t, xb, N);
  chunk_reduce_kernel<<<NCHUNK, 256, 0, stream>>>(degi, partials, N);
  chunk_scan_kernel<<<NCHUNK, 256, 0, stream>>>(degi, partials, NCHUNK, rowptr, dinv, N, E);
  scatter_kernel<<<1024, 256, 0, stream>>>(src32, dst32, rowptr, dinv, degi, epack, E, N);

  // --- conv layer 1 (aggregate 64-wide input, then mm with fused bias+relu) ---
  agg_kernel<64, false><<<gAGG, 256, 0, stream>>>(xb, rowptr, epack, dinv, nullptr, aggX, N);
  mm_mfma<2, true, true><<<gMM, 256, 0, stream>>>(aggX, W1t, b1, bufA, N);
  // --- conv layer 2 ---
  mm_mfma<4, false, false><<<gMM, 256, 0, stream>>>(bufA, W2t, nullptr, bufB, N);
  agg_kernel<128, true><<<gAGG, 256, 0, stream>>>(bufB, rowptr, epack, dinv, b2, bufA, N);
  // --- conv layer 3 ---
  mm_mfma<4, false, false><<<gMM, 256, 0, stream>>>(bufA, W3t, nullptr, bufB, N);
  agg_kernel<128, true><<<gAGG, 256, 0, stream>>>(bufB, rowptr, epack, dinv, b3, bufA, N);
  // --- fused FC head ---
  fc_fused<<<gMM, 256, 0, stream>>>(bufA, F1t, F2t, F3t, fcb1, fcb2, fcb3,
                                    (float*)d_out, N);
}